// Round 6
// baseline (22176.210 us; speedup 1.0000x reference)
//
#include <hip/hip_runtime.h>
#include <hip/hip_bf16.h>
#include <cstdint>
#include <cstddef>

#define T_STEPS 32768
#define DD 64
#define HH 128
#define GG 512   // 4*H

// d_out layout (float32, concatenated flat):
//   step (T,11) @0, experience (T,2) @360448, rsd (T,1) @425984, s (T,1) @458752
#define OFF_EXP 360448
#define OFF_RSD 425984
#define OFF_S   458752

typedef __attribute__((ext_vector_type(8))) _Float16 half8;
typedef __attribute__((ext_vector_type(4))) float f32x4;

__device__ __forceinline__ float exp2_f(float x) {
    float r; asm("v_exp_f32 %0, %1" : "=v"(r) : "v"(x)); return r;
}
__device__ __forceinline__ float sigm_fast(float x) {          // 1/(1+e^-x)
    return __builtin_amdgcn_rcpf(1.0f + exp2_f(x * -1.442695041f));
}
__device__ __forceinline__ float tanh_fast(float x) {          // 1 - 2/(1+e^2x)
    return __builtin_fmaf(
        __builtin_amdgcn_rcpf(1.0f + exp2_f(x * 2.885390082f)), -2.0f, 1.0f);
}

// ---------------------------------------------------------------------------
// Kernel 1: pregate, permuted per-cell: P[r][4*cell + g] = pregate of gate g
// of cell, i.e. thread j computes W row grow = (j&3)*128 + (j>>2).
// ---------------------------------------------------------------------------
__global__ __launch_bounds__(512, 2) void pregate_kernel(
    const float* __restrict__ X, const float* __restrict__ W_ih,
    const float* __restrict__ b_ih, const float* __restrict__ b_hh,
    float* __restrict__ P, int t0, int nrows)
{
    __shared__ __align__(16) float xs[DD];
    const int j = threadIdx.x;
    const int grow = (j & 3) * HH + (j >> 2);

    float w[DD];
    const float4* wv = reinterpret_cast<const float4*>(W_ih + (size_t)grow * DD);
#pragma unroll
    for (int k = 0; k < DD / 4; ++k) {
        float4 v = wv[k];
        w[4*k+0] = v.x; w[4*k+1] = v.y; w[4*k+2] = v.z; w[4*k+3] = v.w;
    }
    const float bias = b_ih[grow] + b_hh[grow];

    const int rpb = (nrows + gridDim.x - 1) / gridDim.x;
    const int r0  = blockIdx.x * rpb;
    const int r1  = (r0 + rpb < nrows) ? (r0 + rpb) : nrows;

    for (int r = r0; r < r1; ++r) {
        const int t = t0 + r;
        if (j < DD) xs[j] = X[(size_t)t * DD + j];
        __syncthreads();
        float acc = bias;
        const float4* xv = reinterpret_cast<const float4*>(xs);
#pragma unroll
        for (int k = 0; k < DD / 4; ++k) {
            float4 v = xv[k];
            acc += v.x*w[4*k+0] + v.y*w[4*k+1] + v.z*w[4*k+2] + v.w*w[4*k+3];
        }
        P[(size_t)r * GG + j] = acc;
        __syncthreads();
    }
}

// ---------------------------------------------------------------------------
// Kernel 2: sequential LSTM, 1 block x 512 threads (8 waves), MFMA matvec
// with LANE-LOCAL cell update:
//   A (op0) = h replicated over 16 rows (4 broadcast ds_read_b128/wave)
//   B (op1) = W_hh columns, tile mt = GATE TYPE mt:
//             col of tile mt is W row (mt*128 + 16w + col)
//   D: rows replicated -> lane (col,kgrp) reg0 of tile mt = gate-mt sum of
//      cell 16w+col. Lane holds all 4 gates of ONE cell: update is in-lane.
// Per step: 4 ds_read_b128 + 16 independent MFMA + 12 adds + 5 exp/rcp
// + 1 ds_write_b16 (kgrp0) / 1 global hist store (kgrp1) + ONE raw barrier.
// ---------------------------------------------------------------------------
__global__ __launch_bounds__(512, 2) void lstm_seq_kernel(
    const float* __restrict__ P, const float* __restrict__ W_hh,
    float* __restrict__ hist, float* __restrict__ state,
    int t0, int C)
{
    __shared__ __align__(16) _Float16 hh2[2][HH];

    const int j      = threadIdx.x;
    const int w      = j >> 6;
    const int l      = j & 63;
    const int col    = l & 15;
    const int kgrp   = l >> 4;          // 0..3
    const int mycell = 16 * w + col;

    // B fragments: wf[mt][kt][e] = W_hh[mt*128 + mycell][32*kt + 8*kgrp + e]
    half8 wf[4][4];
#pragma unroll
    for (int mt = 0; mt < 4; ++mt) {
        const float* wr = W_hh + (size_t)(mt * HH + mycell) * HH + 8 * kgrp;
#pragma unroll
        for (int kt = 0; kt < 4; ++kt) {
            const float* wp = wr + 32 * kt;
            float4 w0 = *reinterpret_cast<const float4*>(wp);
            float4 w1 = *reinterpret_cast<const float4*>(wp + 4);
            half8 hf;
            hf[0] = (_Float16)w0.x; hf[1] = (_Float16)w0.y;
            hf[2] = (_Float16)w0.z; hf[3] = (_Float16)w0.w;
            hf[4] = (_Float16)w1.x; hf[5] = (_Float16)w1.y;
            hf[6] = (_Float16)w1.z; hf[7] = (_Float16)w1.w;
            wf[mt][kt] = hf;
        }
    }

    float c = 0.0f;
    if (t0 != 0) c = state[HH + mycell];            // replicated across kgrp
    if (j < HH) hh2[0][j] = (_Float16)((t0 != 0) ? state[j] : 0.0f);
    __syncthreads();

    const float* Pme = P + 4 * (size_t)mycell;      // this cell's i,f,g,o
    const f32x4 Z = {0.0f, 0.0f, 0.0f, 0.0f};
    f32x4 pc  = *reinterpret_cast<const f32x4*>(Pme);
    f32x4 pn1 = (C > 1) ? *reinterpret_cast<const f32x4*>(Pme + GG) : Z;
    float hn = 0.0f;

#pragma unroll 1
    for (int r = 0; r < C; ++r) {
        // A fragments: h broadcast reads (4 x ds_read_b128, conflict-free)
        const _Float16* hb = &hh2[r & 1][8 * kgrp];
        const half8 a0 = *reinterpret_cast<const half8*>(hb);
        const half8 a1 = *reinterpret_cast<const half8*>(hb + 32);
        const half8 a2 = *reinterpret_cast<const half8*>(hb + 64);
        const half8 a3 = *reinterpret_cast<const half8*>(hb + 96);

        // P prefetch 2 steps ahead (stays in flight across the raw barrier)
        f32x4 pn2 = Z;
        if (r + 2 < C) pn2 = *reinterpret_cast<const f32x4*>(Pme + (size_t)(r + 2) * GG);

#define M(A, B) __builtin_amdgcn_mfma_f32_16x16x32_f16((A), (B), Z, 0, 0, 0)
        // 16 INDEPENDENT MFMAs (no C-chains): d[mt][kt]
        f32x4 d00 = M(a0, wf[0][0]); f32x4 d01 = M(a1, wf[0][1]);
        f32x4 d02 = M(a2, wf[0][2]); f32x4 d03 = M(a3, wf[0][3]);
        f32x4 d10 = M(a0, wf[1][0]); f32x4 d11 = M(a1, wf[1][1]);
        f32x4 d12 = M(a2, wf[1][2]); f32x4 d13 = M(a3, wf[1][3]);
        f32x4 d20 = M(a0, wf[2][0]); f32x4 d21 = M(a1, wf[2][1]);
        f32x4 d22 = M(a2, wf[2][2]); f32x4 d23 = M(a3, wf[2][3]);
        f32x4 d30 = M(a0, wf[3][0]); f32x4 d31 = M(a1, wf[3][1]);
        f32x4 d32 = M(a2, wf[3][2]); f32x4 d33 = M(a3, wf[3][3]);
#undef M
        // kt-partial sums (rows replicated -> reg 0)
        const float si = (d00[0] + d01[0]) + (d02[0] + d03[0]);
        const float sf = (d10[0] + d11[0]) + (d12[0] + d13[0]);
        const float sg = (d20[0] + d21[0]) + (d22[0] + d23[0]);
        const float so = (d30[0] + d31[0]) + (d32[0] + d33[0]);

        // lane-local LSTM cell update (replicated across kgrp groups)
        const float ai = sigm_fast(si + pc[0]);
        const float af = sigm_fast(sf + pc[1]);
        const float ag = tanh_fast(sg + pc[2]);
        const float ao = sigm_fast(so + pc[3]);
        c = __builtin_fmaf(af, c, ai * ag);
        hn = ao * tanh_fast(c);

        if (kgrp == 0)      hh2[(r & 1) ^ 1][mycell] = (_Float16)hn;
        else if (kgrp == 1) hist[(size_t)r * HH + mycell] = hn;

        pc = pn1; pn1 = pn2;

        // one raw barrier: drain LDS only, P loads stay in flight
        asm volatile("s_waitcnt lgkmcnt(0)" ::: "memory");
        __builtin_amdgcn_s_barrier();
        __builtin_amdgcn_sched_barrier(0);
    }

    if (kgrp == 0) {
        state[mycell]      = hn;
        state[HH + mycell] = c;
    }
}

// ---------------------------------------------------------------------------
// Kernel 3: heads, parallel over (t, output)
// ---------------------------------------------------------------------------
__global__ __launch_bounds__(256, 4) void heads_kernel(
    const float* __restrict__ hist,
    const float* __restrict__ W1, const float* __restrict__ b1,
    const float* __restrict__ W2, const float* __restrict__ b2,
    const float* __restrict__ W3, const float* __restrict__ b3,
    const float* __restrict__ W4, const float* __restrict__ b4,
    float* __restrict__ out, int t0, int C)
{
    const int idx = blockIdx.x * 256 + threadIdx.x;
    const int tr  = idx >> 4;
    const int oi  = idx & 15;
    if (tr >= C || oi >= 15) return;

    const float* wrow;
    float bias;
    if (oi < 11)       { wrow = W1 + oi * HH;        bias = b1[oi]; }
    else if (oi < 13)  { wrow = W2 + (oi - 11) * HH; bias = b2[oi - 11]; }
    else if (oi == 13) { wrow = W3;                  bias = b3[0]; }
    else               { wrow = W4;                  bias = b4[0]; }

    const float4* h4 = reinterpret_cast<const float4*>(hist + (size_t)tr * HH);
    const float4* w4 = reinterpret_cast<const float4*>(wrow);
    float s = bias;
#pragma unroll
    for (int k = 0; k < HH / 4; ++k) {
        float4 hv = h4[k];
        float4 wv = w4[k];
        s += hv.x*wv.x + hv.y*wv.y + hv.z*wv.z + hv.w*wv.w;
    }
    const int t = t0 + tr;
    if (oi < 11)       out[(size_t)t * 11 + oi] = s;
    else if (oi < 13)  out[OFF_EXP + (size_t)t * 2 + (oi - 11)] = s;
    else if (oi == 13) out[OFF_RSD + t] = s;
    else               out[OFF_S + t] = s;
}

// ---------------------------------------------------------------------------
extern "C" void kernel_launch(void* const* d_in, const int* in_sizes, int n_in,
                              void* d_out, int out_size, void* d_ws, size_t ws_size,
                              hipStream_t stream)
{
    const float* X    = (const float*)d_in[0];
    const float* W_ih = (const float*)d_in[1];
    const float* W_hh = (const float*)d_in[2];
    const float* b_ih = (const float*)d_in[3];
    const float* b_hh = (const float*)d_in[4];
    const float* W1   = (const float*)d_in[5];
    const float* b1   = (const float*)d_in[6];
    const float* W2   = (const float*)d_in[7];
    const float* b2   = (const float*)d_in[8];
    const float* W3   = (const float*)d_in[9];
    const float* b3   = (const float*)d_in[10];
    const float* W4   = (const float*)d_in[11];
    const float* b4   = (const float*)d_in[12];

    float* out   = (float*)d_out;
    float* state = (float*)d_ws;   // 256 floats: h then c

    // ws: state(1KB) | hist(C*128 f32) | P(C*512 f32)  => 2560 B/row
    size_t avail = (ws_size > 1024) ? (ws_size - 1024) / 2560 : 0;
    int C = (avail >= (size_t)T_STEPS) ? T_STEPS : (int)avail;
    if (C < 1) C = 1;
    float* hist = state + 256;
    float* P    = hist + (size_t)C * HH;

    for (int t0 = 0; t0 < T_STEPS; t0 += C) {
        const int Cc = (C < T_STEPS - t0) ? C : (T_STEPS - t0);
        const int nb = (Cc < 512) ? Cc : 512;
        pregate_kernel<<<nb, 512, 0, stream>>>(X, W_ih, b_ih, b_hh, P, t0, Cc);
        lstm_seq_kernel<<<1, 512, 0, stream>>>(P, W_hh, hist, state, t0, Cc);
        heads_kernel<<<(Cc * 16 + 255) / 256, 256, 0, stream>>>(
            hist, W1, b1, W2, b2, W3, b3, W4, b4, out, t0, Cc);
    }
}

// Round 7
// 20404.308 us; speedup vs baseline: 1.0868x; 1.0868x over previous
//
#include <hip/hip_runtime.h>
#include <hip/hip_bf16.h>
#include <cstdint>
#include <cstddef>

#define T_STEPS 32768
#define DD 64
#define HH 128
#define GG 512   // 4*H

// d_out layout (float32, concatenated flat):
//   step (T,11) @0, experience (T,2) @360448, rsd (T,1) @425984, s (T,1) @458752
#define OFF_EXP 360448
#define OFF_RSD 425984
#define OFF_S   458752

typedef __attribute__((ext_vector_type(8))) _Float16 half8;
typedef __attribute__((ext_vector_type(4))) float f32x4;

__device__ __forceinline__ float exp2_f(float x) {
    float r; asm("v_exp_f32 %0, %1" : "=v"(r) : "v"(x)); return r;
}
__device__ __forceinline__ float sigm_fast(float x) {          // 1/(1+e^-x)
    return __builtin_amdgcn_rcpf(1.0f + exp2_f(x * -1.442695041f));
}
__device__ __forceinline__ float tanh_fast(float x) {          // 1 - 2/(1+e^2x)
    return __builtin_fmaf(
        __builtin_amdgcn_rcpf(1.0f + exp2_f(x * 2.885390082f)), -2.0f, 1.0f);
}

// ---------------------------------------------------------------------------
// Kernel 1: pregate, permuted per-cell: P[r][4*cell + g] = pregate of gate g
// of cell (thread j computes W row grow = (j&3)*128 + (j>>2)).
// ---------------------------------------------------------------------------
__global__ __launch_bounds__(512, 2) void pregate_kernel(
    const float* __restrict__ X, const float* __restrict__ W_ih,
    const float* __restrict__ b_ih, const float* __restrict__ b_hh,
    float* __restrict__ P, int t0, int nrows)
{
    __shared__ __align__(16) float xs[DD];
    const int j = threadIdx.x;
    const int grow = (j & 3) * HH + (j >> 2);

    float w[DD];
    const float4* wv = reinterpret_cast<const float4*>(W_ih + (size_t)grow * DD);
#pragma unroll
    for (int k = 0; k < DD / 4; ++k) {
        float4 v = wv[k];
        w[4*k+0] = v.x; w[4*k+1] = v.y; w[4*k+2] = v.z; w[4*k+3] = v.w;
    }
    const float bias = b_ih[grow] + b_hh[grow];

    const int rpb = (nrows + gridDim.x - 1) / gridDim.x;
    const int r0  = blockIdx.x * rpb;
    const int r1  = (r0 + rpb < nrows) ? (r0 + rpb) : nrows;

    for (int r = r0; r < r1; ++r) {
        const int t = t0 + r;
        if (j < DD) xs[j] = X[(size_t)t * DD + j];
        __syncthreads();
        float acc = bias;
        const float4* xv = reinterpret_cast<const float4*>(xs);
#pragma unroll
        for (int k = 0; k < DD / 4; ++k) {
            float4 v = xv[k];
            acc += v.x*w[4*k+0] + v.y*w[4*k+1] + v.z*w[4*k+2] + v.w*w[4*k+3];
        }
        P[(size_t)r * GG + j] = acc;
        __syncthreads();
    }
}

// ---------------------------------------------------------------------------
// Kernel 2: sequential LSTM, 1 block x 512 threads (8 waves).
// R6 mapping + R5 chained accumulation:
//   A (op0) = h replicated over 16 rows (4 broadcast ds_read_b128/wave)
//   B (op1) = W_hh columns, tile mt = GATE TYPE:
//             col of tile mt is W row (mt*128 + 16w + col)
//   Accumulation: 4 C-chained MFMA streams over kt (one per gate type).
//   D rows replicated -> lane (col,kgrp) reg0 of chain mt = gate-mt sum of
//   cell 16w+col. Lane holds all 4 gates of ONE cell -> lane-local update,
//   replicated across kgrp. kgrp0 publishes h (f16 LDS), kgrp1 stores hist.
// Per step: 4 ds_read_b128 + 16 MFMA (4 chains) + 4 reg reads + 6 trans
// + 1 ds_write_b16 + ONE raw barrier. No gate LDS, no divergent tail.
// ---------------------------------------------------------------------------
__global__ __launch_bounds__(512, 2) void lstm_seq_kernel(
    const float* __restrict__ P, const float* __restrict__ W_hh,
    float* __restrict__ hist, float* __restrict__ state,
    int t0, int C)
{
    __shared__ __align__(16) _Float16 hh2[2][HH];

    const int j      = threadIdx.x;
    const int w      = j >> 6;
    const int l      = j & 63;
    const int col    = l & 15;
    const int kgrp   = l >> 4;          // 0..3
    const int mycell = 16 * w + col;

    // B fragments: wf[mt][kt][e] = W_hh[mt*128 + mycell][32*kt + 8*kgrp + e]
    half8 wf[4][4];
#pragma unroll
    for (int mt = 0; mt < 4; ++mt) {
        const float* wr = W_hh + (size_t)(mt * HH + mycell) * HH + 8 * kgrp;
#pragma unroll
        for (int kt = 0; kt < 4; ++kt) {
            const float* wp = wr + 32 * kt;
            float4 w0 = *reinterpret_cast<const float4*>(wp);
            float4 w1 = *reinterpret_cast<const float4*>(wp + 4);
            half8 hf;
            hf[0] = (_Float16)w0.x; hf[1] = (_Float16)w0.y;
            hf[2] = (_Float16)w0.z; hf[3] = (_Float16)w0.w;
            hf[4] = (_Float16)w1.x; hf[5] = (_Float16)w1.y;
            hf[6] = (_Float16)w1.z; hf[7] = (_Float16)w1.w;
            wf[mt][kt] = hf;
        }
    }

    float c = 0.0f;
    if (t0 != 0) c = state[HH + mycell];            // replicated across kgrp
    if (j < HH) hh2[0][j] = (_Float16)((t0 != 0) ? state[j] : 0.0f);
    __syncthreads();

    const float* Pme = P + 4 * (size_t)mycell;      // this cell's i,f,g,o
    const f32x4 Z = {0.0f, 0.0f, 0.0f, 0.0f};
    f32x4 pc  = *reinterpret_cast<const f32x4*>(Pme);
    f32x4 pn1 = (C > 1) ? *reinterpret_cast<const f32x4*>(Pme + GG) : Z;
    float hn = 0.0f;

#pragma unroll 1
    for (int r = 0; r < C; ++r) {
        // A fragments: h broadcast reads (4 x ds_read_b128, conflict-free)
        const _Float16* hb = &hh2[r & 1][8 * kgrp];
        const half8 a0 = *reinterpret_cast<const half8*>(hb);
        const half8 a1 = *reinterpret_cast<const half8*>(hb + 32);
        const half8 a2 = *reinterpret_cast<const half8*>(hb + 64);
        const half8 a3 = *reinterpret_cast<const half8*>(hb + 96);

        // P prefetch 2 steps ahead (stays in flight across the raw barrier)
        f32x4 pn2 = Z;
        if (r + 2 < C) pn2 = *reinterpret_cast<const f32x4*>(Pme + (size_t)(r + 2) * GG);

        // 4 C-chained MFMA streams (one per gate type), 4 deep over kt
        f32x4 qi = __builtin_amdgcn_mfma_f32_16x16x32_f16(a0, wf[0][0], Z, 0, 0, 0);
        f32x4 qf = __builtin_amdgcn_mfma_f32_16x16x32_f16(a0, wf[1][0], Z, 0, 0, 0);
        f32x4 qg = __builtin_amdgcn_mfma_f32_16x16x32_f16(a0, wf[2][0], Z, 0, 0, 0);
        f32x4 qo = __builtin_amdgcn_mfma_f32_16x16x32_f16(a0, wf[3][0], Z, 0, 0, 0);
        qi = __builtin_amdgcn_mfma_f32_16x16x32_f16(a1, wf[0][1], qi, 0, 0, 0);
        qf = __builtin_amdgcn_mfma_f32_16x16x32_f16(a1, wf[1][1], qf, 0, 0, 0);
        qg = __builtin_amdgcn_mfma_f32_16x16x32_f16(a1, wf[2][1], qg, 0, 0, 0);
        qo = __builtin_amdgcn_mfma_f32_16x16x32_f16(a1, wf[3][1], qo, 0, 0, 0);
        qi = __builtin_amdgcn_mfma_f32_16x16x32_f16(a2, wf[0][2], qi, 0, 0, 0);
        qf = __builtin_amdgcn_mfma_f32_16x16x32_f16(a2, wf[1][2], qf, 0, 0, 0);
        qg = __builtin_amdgcn_mfma_f32_16x16x32_f16(a2, wf[2][2], qg, 0, 0, 0);
        qo = __builtin_amdgcn_mfma_f32_16x16x32_f16(a2, wf[3][2], qo, 0, 0, 0);
        qi = __builtin_amdgcn_mfma_f32_16x16x32_f16(a3, wf[0][3], qi, 0, 0, 0);
        qf = __builtin_amdgcn_mfma_f32_16x16x32_f16(a3, wf[1][3], qf, 0, 0, 0);
        qg = __builtin_amdgcn_mfma_f32_16x16x32_f16(a3, wf[2][3], qg, 0, 0, 0);
        qo = __builtin_amdgcn_mfma_f32_16x16x32_f16(a3, wf[3][3], qo, 0, 0, 0);

        // lane-local LSTM cell update (rows replicated -> reg 0)
        const float ai = sigm_fast(qi[0] + pc[0]);
        const float af = sigm_fast(qf[0] + pc[1]);
        const float ag = tanh_fast(qg[0] + pc[2]);
        const float ao = sigm_fast(qo[0] + pc[3]);
        c = __builtin_fmaf(af, c, ai * ag);
        hn = ao * tanh_fast(c);

        if (kgrp == 0)      hh2[(r & 1) ^ 1][mycell] = (_Float16)hn;
        else if (kgrp == 1) hist[(size_t)r * HH + mycell] = hn;

        pc = pn1; pn1 = pn2;

        // one raw barrier: drain LDS only, P loads stay in flight
        asm volatile("s_waitcnt lgkmcnt(0)" ::: "memory");
        __builtin_amdgcn_s_barrier();
        __builtin_amdgcn_sched_barrier(0);
    }

    if (kgrp == 0) {
        state[mycell]      = hn;
        state[HH + mycell] = c;
    }
}

// ---------------------------------------------------------------------------
// Kernel 3: heads, parallel over (t, output)
// ---------------------------------------------------------------------------
__global__ __launch_bounds__(256, 4) void heads_kernel(
    const float* __restrict__ hist,
    const float* __restrict__ W1, const float* __restrict__ b1,
    const float* __restrict__ W2, const float* __restrict__ b2,
    const float* __restrict__ W3, const float* __restrict__ b3,
    const float* __restrict__ W4, const float* __restrict__ b4,
    float* __restrict__ out, int t0, int C)
{
    const int idx = blockIdx.x * 256 + threadIdx.x;
    const int tr  = idx >> 4;
    const int oi  = idx & 15;
    if (tr >= C || oi >= 15) return;

    const float* wrow;
    float bias;
    if (oi < 11)       { wrow = W1 + oi * HH;        bias = b1[oi]; }
    else if (oi < 13)  { wrow = W2 + (oi - 11) * HH; bias = b2[oi - 11]; }
    else if (oi == 13) { wrow = W3;                  bias = b3[0]; }
    else               { wrow = W4;                  bias = b4[0]; }

    const float4* h4 = reinterpret_cast<const float4*>(hist + (size_t)tr * HH);
    const float4* w4 = reinterpret_cast<const float4*>(wrow);
    float s = bias;
#pragma unroll
    for (int k = 0; k < HH / 4; ++k) {
        float4 hv = h4[k];
        float4 wv = w4[k];
        s += hv.x*wv.x + hv.y*wv.y + hv.z*wv.z + hv.w*wv.w;
    }
    const int t = t0 + tr;
    if (oi < 11)       out[(size_t)t * 11 + oi] = s;
    else if (oi < 13)  out[OFF_EXP + (size_t)t * 2 + (oi - 11)] = s;
    else if (oi == 13) out[OFF_RSD + t] = s;
    else               out[OFF_S + t] = s;
}

// ---------------------------------------------------------------------------
extern "C" void kernel_launch(void* const* d_in, const int* in_sizes, int n_in,
                              void* d_out, int out_size, void* d_ws, size_t ws_size,
                              hipStream_t stream)
{
    const float* X    = (const float*)d_in[0];
    const float* W_ih = (const float*)d_in[1];
    const float* W_hh = (const float*)d_in[2];
    const float* b_ih = (const float*)d_in[3];
    const float* b_hh = (const float*)d_in[4];
    const float* W1   = (const float*)d_in[5];
    const float* b1   = (const float*)d_in[6];
    const float* W2   = (const float*)d_in[7];
    const float* b2   = (const float*)d_in[8];
    const float* W3   = (const float*)d_in[9];
    const float* b3   = (const float*)d_in[10];
    const float* W4   = (const float*)d_in[11];
    const float* b4   = (const float*)d_in[12];

    float* out   = (float*)d_out;
    float* state = (float*)d_ws;   // 256 floats: h then c

    // ws: state(1KB) | hist(C*128 f32) | P(C*512 f32)  => 2560 B/row
    size_t avail = (ws_size > 1024) ? (ws_size - 1024) / 2560 : 0;
    int C = (avail >= (size_t)T_STEPS) ? T_STEPS : (int)avail;
    if (C < 1) C = 1;
    float* hist = state + 256;
    float* P    = hist + (size_t)C * HH;

    for (int t0 = 0; t0 < T_STEPS; t0 += C) {
        const int Cc = (C < T_STEPS - t0) ? C : (T_STEPS - t0);
        const int nb = (Cc < 512) ? Cc : 512;
        pregate_kernel<<<nb, 512, 0, stream>>>(X, W_ih, b_ih, b_hh, P, t0, Cc);
        lstm_seq_kernel<<<1, 512, 0, stream>>>(P, W_hh, hist, state, t0, Cc);
        heads_kernel<<<(Cc * 16 + 255) / 256, 256, 0, stream>>>(
            hist, W1, b1, W2, b2, W3, b3, W4, b4, out, t0, Cc);
    }
}

// Round 8
// 17427.225 us; speedup vs baseline: 1.2725x; 1.1708x over previous
//
#include <hip/hip_runtime.h>
#include <hip/hip_bf16.h>
#include <cstdint>
#include <cstddef>

#define T_STEPS 32768
#define DD 64
#define HH 128
#define GG 512   // 4*H

// d_out layout (float32, concatenated flat):
//   step (T,11) @0, experience (T,2) @360448, rsd (T,1) @425984, s (T,1) @458752
#define OFF_EXP 360448
#define OFF_RSD 425984
#define OFF_S   458752

typedef __attribute__((ext_vector_type(8))) _Float16 half8;
typedef __attribute__((ext_vector_type(4))) float f32x4;

__device__ __forceinline__ float exp2_f(float x) {
    float r; asm("v_exp_f32 %0, %1" : "=v"(r) : "v"(x)); return r;
}
__device__ __forceinline__ float sigm_fast(float x) {          // 1/(1+e^-x)
    return __builtin_amdgcn_rcpf(1.0f + exp2_f(x * -1.442695041f));
}
__device__ __forceinline__ float tanh_fast(float x) {          // 1 - 2/(1+e^2x)
    return __builtin_fmaf(
        __builtin_amdgcn_rcpf(1.0f + exp2_f(x * 2.885390082f)), -2.0f, 1.0f);
}

// ---------------------------------------------------------------------------
// Kernel 1: pregate, permuted per-cell: P[r][4*cell + g] = pregate of gate g
// of cell (thread j computes W row grow = (j&3)*128 + (j>>2)).
// ---------------------------------------------------------------------------
__global__ __launch_bounds__(512, 2) void pregate_kernel(
    const float* __restrict__ X, const float* __restrict__ W_ih,
    const float* __restrict__ b_ih, const float* __restrict__ b_hh,
    float* __restrict__ P, int t0, int nrows)
{
    __shared__ __align__(16) float xs[DD];
    const int j = threadIdx.x;
    const int grow = (j & 3) * HH + (j >> 2);

    float w[DD];
    const float4* wv = reinterpret_cast<const float4*>(W_ih + (size_t)grow * DD);
#pragma unroll
    for (int k = 0; k < DD / 4; ++k) {
        float4 v = wv[k];
        w[4*k+0] = v.x; w[4*k+1] = v.y; w[4*k+2] = v.z; w[4*k+3] = v.w;
    }
    const float bias = b_ih[grow] + b_hh[grow];

    const int rpb = (nrows + gridDim.x - 1) / gridDim.x;
    const int r0  = blockIdx.x * rpb;
    const int r1  = (r0 + rpb < nrows) ? (r0 + rpb) : nrows;

    for (int r = r0; r < r1; ++r) {
        const int t = t0 + r;
        if (j < DD) xs[j] = X[(size_t)t * DD + j];
        __syncthreads();
        float acc = bias;
        const float4* xv = reinterpret_cast<const float4*>(xs);
#pragma unroll
        for (int k = 0; k < DD / 4; ++k) {
            float4 v = xv[k];
            acc += v.x*w[4*k+0] + v.y*w[4*k+1] + v.z*w[4*k+2] + v.w*w[4*k+3];
        }
        P[(size_t)r * GG + j] = acc;
        __syncthreads();
    }
}

// ---------------------------------------------------------------------------
// Kernel 2: sequential LSTM, 1 block x 256 threads = 4 waves (1 per SIMD).
// Wave w owns cells [32w, 32w+32) via TWO chain-sets (col-blocks s=0,1):
//   A (op0) = h replicated over 16 rows (4 broadcast ds_read_b128)
//   B (op1) = W_hh columns; chain (s,mt): col c is W row mt*128+32w+16s+c
//   8 independent C-chained MFMA streams x 4 kt = 32 MFMA.
// Lane (col,kgrp): blk = kgrp>>1 selects its cell 32w+16*blk+col (4 cndmask
// readout), then FULL lane-local cell update (1 cell/lane, no divergence,
// 1 wave/SIMD -> no VALU contention). kgrp0/2 publish h (f16 LDS),
// kgrp1/3 store hist. ONE raw 4-wave barrier per step.
// ---------------------------------------------------------------------------
__global__ __launch_bounds__(256, 1) void lstm_seq_kernel(
    const float* __restrict__ P, const float* __restrict__ W_hh,
    float* __restrict__ hist, float* __restrict__ state,
    int t0, int C)
{
    __shared__ __align__(16) _Float16 hh2[2][HH];

    const int j    = threadIdx.x;
    const int w    = j >> 6;        // wave 0..3
    const int l    = j & 63;
    const int col  = l & 15;
    const int kgrp = l >> 4;        // 0..3
    const int blk  = kgrp >> 1;     // cell block within wave
    const int mycell = 32 * w + 16 * blk + col;
    const bool pubH  = (kgrp & 1) == 0;   // kgrp 0,2 -> LDS h
    const bool pubHist = (kgrp & 1) == 1; // kgrp 1,3 -> hist

    // B fragments: wf[s][mt][kt][e] = W_hh[mt*128+32w+16s+col][32kt+8kgrp+e]
    half8 wf[2][4][4];
#pragma unroll
    for (int s = 0; s < 2; ++s) {
#pragma unroll
        for (int mt = 0; mt < 4; ++mt) {
            const float* wr =
                W_hh + (size_t)(mt * HH + 32 * w + 16 * s + col) * HH + 8 * kgrp;
#pragma unroll
            for (int kt = 0; kt < 4; ++kt) {
                const float* wp = wr + 32 * kt;
                float4 w0 = *reinterpret_cast<const float4*>(wp);
                float4 w1 = *reinterpret_cast<const float4*>(wp + 4);
                half8 hf;
                hf[0] = (_Float16)w0.x; hf[1] = (_Float16)w0.y;
                hf[2] = (_Float16)w0.z; hf[3] = (_Float16)w0.w;
                hf[4] = (_Float16)w1.x; hf[5] = (_Float16)w1.y;
                hf[6] = (_Float16)w1.z; hf[7] = (_Float16)w1.w;
                wf[s][mt][kt] = hf;
            }
        }
    }

    float c = 0.0f;
    if (t0 != 0) c = state[HH + mycell];           // replicated across pair
    // init h LDS (first 128 threads cover all cells)
    if (j < HH) hh2[0][j] = (_Float16)((t0 != 0) ? state[j] : 0.0f);
    __syncthreads();

    const float* Pme = P + 4 * (size_t)mycell;     // this cell's i,f,g,o
    const f32x4 Z = {0.0f, 0.0f, 0.0f, 0.0f};
    f32x4 pc  = *reinterpret_cast<const f32x4*>(Pme);
    f32x4 pn1 = (C > 1) ? *reinterpret_cast<const f32x4*>(Pme + GG) : Z;
    float hn = 0.0f;

#pragma unroll 1
    for (int r = 0; r < C; ++r) {
        // A fragments: h broadcast reads (4 x ds_read_b128, conflict-free)
        const _Float16* hb = &hh2[r & 1][8 * kgrp];
        const half8 a0 = *reinterpret_cast<const half8*>(hb);
        const half8 a1 = *reinterpret_cast<const half8*>(hb + 32);
        const half8 a2 = *reinterpret_cast<const half8*>(hb + 64);
        const half8 a3 = *reinterpret_cast<const half8*>(hb + 96);

        // P prefetch 2 steps ahead (in flight across the raw barrier)
        f32x4 pn2 = Z;
        if (r + 2 < C) pn2 = *reinterpret_cast<const f32x4*>(Pme + (size_t)(r + 2) * GG);

        // 8 independent chains (2 col-blocks x 4 gates), 4 deep over kt
        f32x4 qa0, qa1, qa2, qa3, qb0, qb1, qb2, qb3;
#define MF(A, B, Cc) __builtin_amdgcn_mfma_f32_16x16x32_f16((A), (B), (Cc), 0, 0, 0)
        qa0 = MF(a0, wf[0][0][0], Z); qa1 = MF(a0, wf[0][1][0], Z);
        qa2 = MF(a0, wf[0][2][0], Z); qa3 = MF(a0, wf[0][3][0], Z);
        qb0 = MF(a0, wf[1][0][0], Z); qb1 = MF(a0, wf[1][1][0], Z);
        qb2 = MF(a0, wf[1][2][0], Z); qb3 = MF(a0, wf[1][3][0], Z);

        qa0 = MF(a1, wf[0][0][1], qa0); qa1 = MF(a1, wf[0][1][1], qa1);
        qa2 = MF(a1, wf[0][2][1], qa2); qa3 = MF(a1, wf[0][3][1], qa3);
        qb0 = MF(a1, wf[1][0][1], qb0); qb1 = MF(a1, wf[1][1][1], qb1);
        qb2 = MF(a1, wf[1][2][1], qb2); qb3 = MF(a1, wf[1][3][1], qb3);

        qa0 = MF(a2, wf[0][0][2], qa0); qa1 = MF(a2, wf[0][1][2], qa1);
        qa2 = MF(a2, wf[0][2][2], qa2); qa3 = MF(a2, wf[0][3][2], qa3);
        qb0 = MF(a2, wf[1][0][2], qb0); qb1 = MF(a2, wf[1][1][2], qb1);
        qb2 = MF(a2, wf[1][2][2], qb2); qb3 = MF(a2, wf[1][3][2], qb3);

        qa0 = MF(a3, wf[0][0][3], qa0); qa1 = MF(a3, wf[0][1][3], qa1);
        qa2 = MF(a3, wf[0][2][3], qa2); qa3 = MF(a3, wf[0][3][3], qa3);
        qb0 = MF(a3, wf[1][0][3], qb0); qb1 = MF(a3, wf[1][1][3], qb1);
        qb2 = MF(a3, wf[1][2][3], qb2); qb3 = MF(a3, wf[1][3][3], qb3);
#undef MF

        // readout: pick this lane's cell block (rows replicated -> reg 0)
        const bool useB = (blk != 0);
        const float si = useB ? qb0[0] : qa0[0];
        const float sf = useB ? qb1[0] : qa1[0];
        const float sg = useB ? qb2[0] : qa2[0];
        const float so = useB ? qb3[0] : qa3[0];

        // lane-local LSTM cell update (1 cell per lane)
        const float ai = sigm_fast(si + pc[0]);
        const float af = sigm_fast(sf + pc[1]);
        const float ag = tanh_fast(sg + pc[2]);
        const float ao = sigm_fast(so + pc[3]);
        c = __builtin_fmaf(af, c, ai * ag);
        hn = ao * tanh_fast(c);

        if (pubH)         hh2[(r & 1) ^ 1][mycell] = (_Float16)hn;
        else if (pubHist) hist[(size_t)r * HH + mycell] = hn;

        pc = pn1; pn1 = pn2;

        // one raw barrier: drain LDS only, global loads stay in flight
        asm volatile("s_waitcnt lgkmcnt(0)" ::: "memory");
        __builtin_amdgcn_s_barrier();
        __builtin_amdgcn_sched_barrier(0);
    }

    if (pubH) {
        state[mycell]      = hn;
        state[HH + mycell] = c;
    }
}

// ---------------------------------------------------------------------------
// Kernel 3: heads, parallel over (t, output)
// ---------------------------------------------------------------------------
__global__ __launch_bounds__(256, 4) void heads_kernel(
    const float* __restrict__ hist,
    const float* __restrict__ W1, const float* __restrict__ b1,
    const float* __restrict__ W2, const float* __restrict__ b2,
    const float* __restrict__ W3, const float* __restrict__ b3,
    const float* __restrict__ W4, const float* __restrict__ b4,
    float* __restrict__ out, int t0, int C)
{
    const int idx = blockIdx.x * 256 + threadIdx.x;
    const int tr  = idx >> 4;
    const int oi  = idx & 15;
    if (tr >= C || oi >= 15) return;

    const float* wrow;
    float bias;
    if (oi < 11)       { wrow = W1 + oi * HH;        bias = b1[oi]; }
    else if (oi < 13)  { wrow = W2 + (oi - 11) * HH; bias = b2[oi - 11]; }
    else if (oi == 13) { wrow = W3;                  bias = b3[0]; }
    else               { wrow = W4;                  bias = b4[0]; }

    const float4* h4 = reinterpret_cast<const float4*>(hist + (size_t)tr * HH);
    const float4* w4 = reinterpret_cast<const float4*>(wrow);
    float s = bias;
#pragma unroll
    for (int k = 0; k < HH / 4; ++k) {
        float4 hv = h4[k];
        float4 wv = w4[k];
        s += hv.x*wv.x + hv.y*wv.y + hv.z*wv.z + hv.w*wv.w;
    }
    const int t = t0 + tr;
    if (oi < 11)       out[(size_t)t * 11 + oi] = s;
    else if (oi < 13)  out[OFF_EXP + (size_t)t * 2 + (oi - 11)] = s;
    else if (oi == 13) out[OFF_RSD + t] = s;
    else               out[OFF_S + t] = s;
}

// ---------------------------------------------------------------------------
extern "C" void kernel_launch(void* const* d_in, const int* in_sizes, int n_in,
                              void* d_out, int out_size, void* d_ws, size_t ws_size,
                              hipStream_t stream)
{
    const float* X    = (const float*)d_in[0];
    const float* W_ih = (const float*)d_in[1];
    const float* W_hh = (const float*)d_in[2];
    const float* b_ih = (const float*)d_in[3];
    const float* b_hh = (const float*)d_in[4];
    const float* W1   = (const float*)d_in[5];
    const float* b1   = (const float*)d_in[6];
    const float* W2   = (const float*)d_in[7];
    const float* b2   = (const float*)d_in[8];
    const float* W3   = (const float*)d_in[9];
    const float* b3   = (const float*)d_in[10];
    const float* W4   = (const float*)d_in[11];
    const float* b4   = (const float*)d_in[12];

    float* out   = (float*)d_out;
    float* state = (float*)d_ws;   // 256 floats: h then c

    // ws: state(1KB) | hist(C*128 f32) | P(C*512 f32)  => 2560 B/row
    size_t avail = (ws_size > 1024) ? (ws_size - 1024) / 2560 : 0;
    int C = (avail >= (size_t)T_STEPS) ? T_STEPS : (int)avail;
    if (C < 1) C = 1;
    float* hist = state + 256;
    float* P    = hist + (size_t)C * HH;

    for (int t0 = 0; t0 < T_STEPS; t0 += C) {
        const int Cc = (C < T_STEPS - t0) ? C : (T_STEPS - t0);
        const int nb = (Cc < 512) ? Cc : 512;
        pregate_kernel<<<nb, 512, 0, stream>>>(X, W_ih, b_ih, b_hh, P, t0, Cc);
        lstm_seq_kernel<<<1, 256, 0, stream>>>(P, W_hh, hist, state, t0, Cc);
        heads_kernel<<<(Cc * 16 + 255) / 256, 256, 0, stream>>>(
            hist, W1, b1, W2, b2, W3, b3, W4, b4, out, t0, Cc);
    }
}